// Round 1
// baseline (259.055 us; speedup 1.0000x reference)
//
#include <hip/hip_runtime.h>

#define NB 32
#define NN 1024
#define DINR 144

typedef __attribute__((ext_vector_type(4))) float f4;
typedef __attribute__((ext_vector_type(8))) short s8;

// ws float offsets
#define OFF_A  (0u)
#define OFF_B0 (1u*NB*64*NN)
#define OFF_B1 (2u*NB*64*NN)
#define OFF_C  (3u*NB*64*NN)
#define OFF_UP (4u*NB*64*NN)
#define OFF_NS (OFF_UP + NB*8*64*16)

// ---------------------------------------------------------------------------
// k_init: blocks [0,128): compute A = E@x[16:48], B0 = E@x[48:80] (col-major),
//                          C = x[80:144]
//         blocks [128,640): nstar[b][m] = argmax_{n<1008} X[:,m]·X[:,n]
//                           via bf16 MFMA 16x16x32 (K=16 zero-padded)
// ---------------------------------------------------------------------------
__global__ __launch_bounds__(256) void k_init(
    const float* __restrict__ x, const float* __restrict__ emb,
    float* __restrict__ A, float* __restrict__ Bt, float* __restrict__ C,
    int* __restrict__ nstar)
{
  __shared__ unsigned int XT[NN * 8];   // bf16-pair packed X^T : XT[n][k/2]
  int t = threadIdx.x;
  if (blockIdx.x < 128) {
    int b = blockIdx.x >> 2;
    int n = ((blockIdx.x & 3) << 8) + t;
    const float* xb = x + (size_t)b * DINR * NN;
    const f4* E4 = reinterpret_cast<const f4*>(emb);
    float xa[32];
    #pragma unroll
    for (int c = 0; c < 32; c++) xa[c] = xb[(16 + c) * NN + n];
    float* Ab = A + (size_t)b * 64 * NN;
    for (int j = 0; j < 64; j++) {
      float acc = 0.f;
      #pragma unroll
      for (int cc = 0; cc < 8; cc++) {
        f4 e = E4[j * 8 + cc];
        acc += e[0]*xa[4*cc] + e[1]*xa[4*cc+1] + e[2]*xa[4*cc+2] + e[3]*xa[4*cc+3];
      }
      Ab[j * NN + n] = acc;
    }
    #pragma unroll
    for (int c = 0; c < 32; c++) xa[c] = xb[(48 + c) * NN + n];
    float* Bb = Bt + ((size_t)b * NN + n) * 64;   // column-major rows of 64
    for (int j = 0; j < 64; j++) {
      float acc = 0.f;
      #pragma unroll
      for (int cc = 0; cc < 8; cc++) {
        f4 e = E4[j * 8 + cc];
        acc += e[0]*xa[4*cc] + e[1]*xa[4*cc+1] + e[2]*xa[4*cc+2] + e[3]*xa[4*cc+3];
      }
      Bb[j] = acc;
    }
    float* Cb = C + (size_t)b * 64 * NN;
    for (int j = 0; j < 64; j++) Cb[j * NN + n] = xb[(80 + j) * NN + n];
  } else {
    int a = blockIdx.x - 128;
    int b = a >> 4;
    int mg = a & 15;
    const float* xb = x + (size_t)b * DINR * NN;
    #pragma unroll
    for (int rep = 0; rep < 4; rep++) {
      int n = t + (rep << 8);
      unsigned int pk[8];
      #pragma unroll
      for (int h = 0; h < 8; h++) {
        unsigned int u0 = __float_as_uint(xb[(2*h) * NN + n]);
        unsigned int u1 = __float_as_uint(xb[(2*h+1) * NN + n]);
        pk[h] = (u0 >> 16) | (u1 & 0xFFFF0000u);   // bf16 truncate, pack pair
      }
      #pragma unroll
      for (int h = 0; h < 8; h++) XT[n * 8 + h] = pk[h];
    }
    __syncthreads();
    int w = t >> 6;           // wave -> m-tile
    int lane = t & 63;
    int r = lane & 15;
    int g = lane >> 4;
    int mt = mg * 64 + w * 16;
    s8 zero8 = {0,0,0,0,0,0,0,0};
    s8 afrag = zero8;
    if (g < 2) afrag = *reinterpret_cast<const s8*>(&XT[(mt + r) * 8 + g * 4]);
    float bestv[4];
    int besti[4];
    #pragma unroll
    for (int j = 0; j < 4; j++) { bestv[j] = -3.4e38f; besti[j] = 0x7FFFFFFF; }
    for (int nt = 0; nt < 63; nt++) {
      s8 bfrag = zero8;
      if (g < 2) bfrag = *reinterpret_cast<const s8*>(&XT[(nt*16 + r) * 8 + g * 4]);
      f4 acc = {0.f, 0.f, 0.f, 0.f};
      acc = __builtin_amdgcn_mfma_f32_16x16x32_bf16(afrag, bfrag, acc, 0, 0, 0);
      int n = nt * 16 + r;   // D col = lane&15
      #pragma unroll
      for (int j = 0; j < 4; j++) {   // D row = (lane>>4)*4 + j
        float v = acc[j];
        bool better = (v > bestv[j]) || (v == bestv[j] && n < besti[j]);
        if (better) { bestv[j] = v; besti[j] = n; }
      }
    }
    #pragma unroll
    for (int s = 1; s < 16; s <<= 1) {
      #pragma unroll
      for (int j = 0; j < 4; j++) {
        float ov = __shfl_xor(bestv[j], s, 64);
        int   oi = __shfl_xor(besti[j], s, 64);
        bool better = (ov > bestv[j]) || (ov == bestv[j] && oi < besti[j]);
        if (better) { bestv[j] = ov; besti[j] = oi; }
      }
    }
    if (r == 0) {
      #pragma unroll
      for (int j = 0; j < 4; j++)
        nstar[b * NN + mt + g * 4 + j] = besti[j];
    }
  }
}

// ---------------------------------------------------------------------------
// k_upart: partial U = (alpha ∘ (A - B)) @ Xkv^T  over n-chunk of 126
// grid 256 = 32 batches x 8 chunks; thread t: j = t>>2 (64), g = t&3 (i-quad)
// ---------------------------------------------------------------------------
__global__ __launch_bounds__(256) void k_upart(
    const float* __restrict__ x, const float* __restrict__ alpha, int l,
    const float* __restrict__ A, const float* __restrict__ Bin,
    float* __restrict__ Up)
{
  int b = blockIdx.x >> 3;
  int ch = blockIdx.x & 7;
  int t = threadIdx.x;
  int j = t >> 2;
  int g = t & 3;
  float al = alpha[l * 64 + j];
  const float* xb = x + (size_t)b * DINR * NN;
  const float* Ar = A + ((size_t)b * 64 + j) * NN;
  const float* Bb = Bin + (size_t)b * NN * 64;
  const float* x0 = xb + (4*g + 0) * NN;
  const float* x1 = xb + (4*g + 1) * NN;
  const float* x2 = xb + (4*g + 2) * NN;
  const float* x3 = xb + (4*g + 3) * NN;
  float a0 = 0.f, a1 = 0.f, a2 = 0.f, a3 = 0.f;
  int n0 = ch * 126;
  #pragma unroll 2
  for (int n = n0; n < n0 + 126; n++) {
    float w = al * (Ar[n] - Bb[n * 64 + j]);
    a0 += w * x0[n]; a1 += w * x1[n]; a2 += w * x2[n]; a3 += w * x3[n];
  }
  float* up = Up + (((size_t)b * 8 + ch) * 64 + j) * 16 + g * 4;
  up[0] = a0; up[1] = a1; up[2] = a2; up[3] = a3;
}

// ---------------------------------------------------------------------------
// k_update: combine U; C[:,m] += (kp/M) U @ X[:,m];
//           p = softmax(E^T C'); B_out[:,m] = B[:,m] - B[:,nstar]/M + E p
//           last layer: write logits (=E^T C') and predictions (=p)
// grid 128 = 32 batches x 4 m-tiles of 256; thread = one column m
// ---------------------------------------------------------------------------
__global__ __launch_bounds__(256) void k_update(
    const float* __restrict__ x, const float* __restrict__ emb,
    const float* __restrict__ kpp,
    const float* __restrict__ Up, const int* __restrict__ nstar,
    float* __restrict__ C, const float* __restrict__ Bin,
    float* __restrict__ Bout, int last, float* __restrict__ out)
{
  __shared__ float U[1024];
  int t = threadIdx.x;
  int b = blockIdx.x >> 2;
  int m = ((blockIdx.x & 3) << 8) + t;
  for (int idx = t; idx < 1024; idx += 256) {
    float s = 0.f;
    #pragma unroll
    for (int c = 0; c < 8; c++) s += Up[((size_t)b * 8 + c) * 1024 + idx];
    U[idx] = s;
  }
  __syncthreads();
  const f4* E4 = reinterpret_cast<const f4*>(emb);
  float sc = kpp[0] * (1.0f / 1008.0f);
  const float* xb = x + (size_t)b * DINR * NN;
  float X[16];
  #pragma unroll
  for (int i = 0; i < 16; i++) X[i] = xb[i * NN + m];
  float lg[32];
  #pragma unroll
  for (int c = 0; c < 32; c++) lg[c] = 0.f;
  float* Cb = C + (size_t)b * 64 * NN + m;
  const f4* U4 = reinterpret_cast<const f4*>(U);
  #pragma unroll 2
  for (int j = 0; j < 64; j++) {
    float d = 0.f;
    #pragma unroll
    for (int ii = 0; ii < 4; ii++) {
      f4 u = U4[j * 4 + ii];
      d += u[0]*X[4*ii] + u[1]*X[4*ii+1] + u[2]*X[4*ii+2] + u[3]*X[4*ii+3];
    }
    float cn = Cb[j * NN] + sc * d;
    Cb[j * NN] = cn;
    #pragma unroll
    for (int cc = 0; cc < 8; cc++) {
      f4 e = E4[j * 8 + cc];
      lg[4*cc+0] += cn * e[0]; lg[4*cc+1] += cn * e[1];
      lg[4*cc+2] += cn * e[2]; lg[4*cc+3] += cn * e[3];
    }
  }
  if (last) {
    float* lo = out + ((size_t)b * NN + m) * 32;
    #pragma unroll
    for (int c = 0; c < 32; c++) lo[c] = lg[c];
  }
  float mx = lg[0];
  #pragma unroll
  for (int c = 1; c < 32; c++) mx = fmaxf(mx, lg[c]);
  float ssum = 0.f;
  #pragma unroll
  for (int c = 0; c < 32; c++) { lg[c] = __expf(lg[c] - mx); ssum += lg[c]; }
  float inv = 1.0f / ssum;
  #pragma unroll
  for (int c = 0; c < 32; c++) lg[c] *= inv;
  if (last) {
    float* po = out + (size_t)NB * NN * 32 + ((size_t)b * NN + m) * 32;
    #pragma unroll
    for (int c = 0; c < 32; c++) po[c] = lg[c];
  }
  int nst = nstar[b * NN + m];
  const f4* BC = reinterpret_cast<const f4*>(Bin + ((size_t)b * NN + m) * 64);
  const f4* BG = reinterpret_cast<const f4*>(Bin + ((size_t)b * NN + nst) * 64);
  f4* BO = reinterpret_cast<f4*>(Bout + ((size_t)b * NN + m) * 64);
  const float invM = 1.0f / 1008.0f;
  #pragma unroll 2
  for (int jg = 0; jg < 16; jg++) {
    f4 bc4 = BC[jg];
    f4 bg4 = BG[jg];
    f4 vo;
    #pragma unroll
    for (int k = 0; k < 4; k++) {
      int j = jg * 4 + k;
      float v = bc4[k] - bg4[k] * invM;
      #pragma unroll
      for (int cc = 0; cc < 8; cc++) {
        f4 e = E4[j * 8 + cc];
        v += e[0]*lg[4*cc] + e[1]*lg[4*cc+1] + e[2]*lg[4*cc+2] + e[3]*lg[4*cc+3];
      }
      vo[k] = v;
    }
    BO[jg] = vo;
  }
}

extern "C" void kernel_launch(void* const* d_in, const int* in_sizes, int n_in,
                              void* d_out, int out_size, void* d_ws, size_t ws_size,
                              hipStream_t stream)
{
  const float* x     = (const float*)d_in[0];
  const float* alpha = (const float*)d_in[1];
  const float* kp    = (const float*)d_in[2];
  const float* emb   = (const float*)d_in[3];
  float* ws = (float*)d_ws;
  float* A  = ws + OFF_A;
  float* B0 = ws + OFF_B0;
  float* B1 = ws + OFF_B1;
  float* C  = ws + OFF_C;
  float* Up = ws + OFF_UP;
  int*   ns = (int*)(ws + OFF_NS);
  float* out = (float*)d_out;

  k_init<<<640, 256, 0, stream>>>(x, emb, A, B0, C, ns);
  float* Bbuf[2] = {B0, B1};
  for (int l = 0; l < 3; l++) {
    k_upart<<<256, 256, 0, stream>>>(x, alpha, l, A, Bbuf[l & 1], Up);
    k_update<<<128, 256, 0, stream>>>(x, emb, kp, Up, ns, C, Bbuf[l & 1],
                                      Bbuf[(l + 1) & 1], (l == 2) ? 1 : 0, out);
  }
}

// Round 2
// 185.835 us; speedup vs baseline: 1.3940x; 1.3940x over previous
//
#include <hip/hip_runtime.h>

#define NB 32
#define NN 1024
#define DINR 144

typedef __attribute__((ext_vector_type(4))) float f4;
typedef __attribute__((ext_vector_type(8))) short s8;

// ws float offsets
#define OFF_A  (0u)
#define OFF_B0 (1u*NB*64*NN)
#define OFF_B1 (2u*NB*64*NN)
#define OFF_C  (3u*NB*64*NN)
#define OFF_UP (4u*NB*64*NN)
#define OFF_NS (OFF_UP + NB*16*64*16)

// ---------------------------------------------------------------------------
// k_init: blocks [0,1024): b=blk>>5, ctile=blk&31 (32 cols). 8 threads/col:
//         A = E@x[16:48] (row-major), B0 = E@x[48:80] (col-major), C = x[80:144]
//         blocks [1024,1536): nstar[b][m] = argmax_{n<1008} X[:,m]·X[:,n]
//         via bf16 MFMA 16x16x32 (K=16 zero-padded)
// ---------------------------------------------------------------------------
__global__ __launch_bounds__(256) void k_init(
    const float* __restrict__ x, const float* __restrict__ emb,
    float* __restrict__ A, float* __restrict__ Bt, float* __restrict__ C,
    int* __restrict__ nstar)
{
  __shared__ unsigned int XT[NN * 8];   // bf16-pair packed X^T (argmax part)
  int t = threadIdx.x;
  if (blockIdx.x < 1024) {
    int b = blockIdx.x >> 5;
    int ct = blockIdx.x & 31;
    int c = t >> 3;
    int g = t & 7;
    int n = ct * 32 + c;
    const float* xb = x + (size_t)b * DINR * NN;
    const f4* E4 = reinterpret_cast<const f4*>(emb);
    float xa[32];
    // A rows g*8..g*8+7
    #pragma unroll
    for (int cc = 0; cc < 32; cc++) xa[cc] = xb[(16 + cc) * NN + n];
    float* Ab = A + (size_t)b * 64 * NN;
    #pragma unroll
    for (int jj = 0; jj < 8; jj++) {
      int j = g * 8 + jj;
      float acc = 0.f;
      #pragma unroll
      for (int cc = 0; cc < 8; cc++) {
        f4 e = E4[j * 8 + cc];
        acc += e[0]*xa[4*cc] + e[1]*xa[4*cc+1] + e[2]*xa[4*cc+2] + e[3]*xa[4*cc+3];
      }
      Ab[j * NN + n] = acc;
    }
    // B (col-major)
    #pragma unroll
    for (int cc = 0; cc < 32; cc++) xa[cc] = xb[(48 + cc) * NN + n];
    float bacc[8];
    #pragma unroll
    for (int jj = 0; jj < 8; jj++) {
      int j = g * 8 + jj;
      float acc = 0.f;
      #pragma unroll
      for (int cc = 0; cc < 8; cc++) {
        f4 e = E4[j * 8 + cc];
        acc += e[0]*xa[4*cc] + e[1]*xa[4*cc+1] + e[2]*xa[4*cc+2] + e[3]*xa[4*cc+3];
      }
      bacc[jj] = acc;
    }
    float* Bb = Bt + ((size_t)b * NN + n) * 64 + g * 8;
    f4 v0 = {bacc[0], bacc[1], bacc[2], bacc[3]};
    f4 v1 = {bacc[4], bacc[5], bacc[6], bacc[7]};
    reinterpret_cast<f4*>(Bb)[0] = v0;
    reinterpret_cast<f4*>(Bb)[1] = v1;
    // C copy rows g*8..
    float* Cb = C + (size_t)b * 64 * NN;
    #pragma unroll
    for (int jj = 0; jj < 8; jj++) {
      int j = g * 8 + jj;
      Cb[j * NN + n] = xb[(80 + j) * NN + n];
    }
  } else {
    int a = blockIdx.x - 1024;
    int b = a >> 4;
    int mg = a & 15;
    const float* xb = x + (size_t)b * DINR * NN;
    #pragma unroll
    for (int rep = 0; rep < 4; rep++) {
      int n = t + (rep << 8);
      unsigned int pk[8];
      #pragma unroll
      for (int h = 0; h < 8; h++) {
        unsigned int u0 = __float_as_uint(xb[(2*h) * NN + n]);
        unsigned int u1 = __float_as_uint(xb[(2*h+1) * NN + n]);
        pk[h] = (u0 >> 16) | (u1 & 0xFFFF0000u);   // bf16 truncate, pack pair
      }
      #pragma unroll
      for (int h = 0; h < 8; h++) XT[n * 8 + h] = pk[h];
    }
    __syncthreads();
    int w = t >> 6;           // wave -> m-tile
    int lane = t & 63;
    int r = lane & 15;
    int g = lane >> 4;
    int mt = mg * 64 + w * 16;
    s8 zero8 = {0,0,0,0,0,0,0,0};
    s8 afrag = zero8;
    if (g < 2) afrag = *reinterpret_cast<const s8*>(&XT[(mt + r) * 8 + g * 4]);
    float bestv[4];
    int besti[4];
    #pragma unroll
    for (int j = 0; j < 4; j++) { bestv[j] = -3.4e38f; besti[j] = 0x7FFFFFFF; }
    for (int nt = 0; nt < 63; nt++) {
      s8 bfrag = zero8;
      if (g < 2) bfrag = *reinterpret_cast<const s8*>(&XT[(nt*16 + r) * 8 + g * 4]);
      f4 acc = {0.f, 0.f, 0.f, 0.f};
      acc = __builtin_amdgcn_mfma_f32_16x16x32_bf16(afrag, bfrag, acc, 0, 0, 0);
      int n = nt * 16 + r;   // D col = lane&15
      #pragma unroll
      for (int j = 0; j < 4; j++) {   // D row = (lane>>4)*4 + j
        float v = acc[j];
        bool better = (v > bestv[j]) || (v == bestv[j] && n < besti[j]);
        if (better) { bestv[j] = v; besti[j] = n; }
      }
    }
    #pragma unroll
    for (int s = 1; s < 16; s <<= 1) {
      #pragma unroll
      for (int j = 0; j < 4; j++) {
        float ov = __shfl_xor(bestv[j], s, 64);
        int   oi = __shfl_xor(besti[j], s, 64);
        bool better = (ov > bestv[j]) || (ov == bestv[j] && oi < besti[j]);
        if (better) { bestv[j] = ov; besti[j] = oi; }
      }
    }
    if (r == 0) {
      #pragma unroll
      for (int j = 0; j < 4; j++)
        nstar[b * NN + mt + g * 4 + j] = besti[j];
    }
  }
}

// ---------------------------------------------------------------------------
// k_upart: partial U = (alpha ∘ (A - B)) @ Xkv^T  over n-chunk of 63
// grid 512 = 32 batches x 16 chunks; thread t: j = t>>2 (64), g = t&3 (i-quad)
// ---------------------------------------------------------------------------
__global__ __launch_bounds__(256) void k_upart(
    const float* __restrict__ x, const float* __restrict__ alpha, int l,
    const float* __restrict__ A, const float* __restrict__ Bin,
    float* __restrict__ Up)
{
  int b = blockIdx.x >> 4;
  int ch = blockIdx.x & 15;
  int t = threadIdx.x;
  int j = t >> 2;
  int g = t & 3;
  float al = alpha[l * 64 + j];
  const float* xb = x + (size_t)b * DINR * NN;
  const float* Ar = A + ((size_t)b * 64 + j) * NN;
  const float* Bb = Bin + (size_t)b * NN * 64;
  const float* x0 = xb + (4*g + 0) * NN;
  const float* x1 = xb + (4*g + 1) * NN;
  const float* x2 = xb + (4*g + 2) * NN;
  const float* x3 = xb + (4*g + 3) * NN;
  float a0 = 0.f, a1 = 0.f, a2 = 0.f, a3 = 0.f;
  int n0 = ch * 63;
  #pragma unroll 3
  for (int n = n0; n < n0 + 63; n++) {
    float w = al * (Ar[n] - Bb[n * 64 + j]);
    a0 += w * x0[n]; a1 += w * x1[n]; a2 += w * x2[n]; a3 += w * x3[n];
  }
  float* up = Up + (((size_t)b * 16 + ch) * 64 + j) * 16 + g * 4;
  up[0] = a0; up[1] = a1; up[2] = a2; up[3] = a3;
}

// ---------------------------------------------------------------------------
// k_update: combine U; C[:,m] += (kp/M) U @ X[:,m];
//           p = softmax(E^T C'); B_out[:,m] = B[:,m] - B[:,nstar]/M + E p
//           last layer: write logits (=E^T C') and predictions (=p)
// grid 1024 = 32 b x 32 m-tiles of 32 cols; 8 threads per column:
//   c = t>>3 (column), g = t&7 (j-octet). Logits tree-reduced via shfl_xor.
// U and E staged in LDS with XOR swizzle (j-group vs quad) -> no bank conflict
// ---------------------------------------------------------------------------
__global__ __launch_bounds__(256) void k_update(
    const float* __restrict__ x, const float* __restrict__ emb,
    const float* __restrict__ kpp,
    const float* __restrict__ Up, const int* __restrict__ nstar,
    float* __restrict__ C, const float* __restrict__ Bin,
    float* __restrict__ Bout, int last, float* __restrict__ out)
{
  __shared__ float U[1024];     // [j][quad swizzled]
  __shared__ f4 Es[512];        // [j][cc swizzled]
  int t = threadIdx.x;
  int b = blockIdx.x >> 5;
  int mt = blockIdx.x & 31;
  int c = t >> 3;
  int g = t & 7;
  int m = mt * 32 + c;
  // combine 16 U-partials -> LDS (swizzled)
  for (int idx = t; idx < 1024; idx += 256) {
    float s = 0.f;
    #pragma unroll
    for (int ch = 0; ch < 16; ch++) s += Up[((size_t)b * 16 + ch) * 1024 + idx];
    int j = idx >> 4, i = idx & 15;
    U[j * 16 + ((((i >> 2) ^ (j >> 3)) & 3) << 2) + (i & 3)] = s;
  }
  // stage E -> LDS (swizzled)
  const f4* E4g = reinterpret_cast<const f4*>(emb);
  for (int fj = t; fj < 512; fj += 256) {
    int j = fj >> 3, cc = fj & 7;
    Es[j * 8 + ((cc ^ (j >> 3)) & 7)] = E4g[fj];
  }
  __syncthreads();
  float sc = kpp[0] * (1.0f / 1008.0f);
  const float* xb = x + (size_t)b * DINR * NN;
  float X[16];
  #pragma unroll
  for (int i = 0; i < 16; i++) X[i] = xb[i * NN + m];
  float lg[32];
  #pragma unroll
  for (int k = 0; k < 32; k++) lg[k] = 0.f;
  float* Cb = C + (size_t)b * 64 * NN + m;
  const f4* U4 = reinterpret_cast<const f4*>(U);
  #pragma unroll
  for (int jj = 0; jj < 8; jj++) {
    int j = g * 8 + jj;
    float d = 0.f;
    #pragma unroll
    for (int ii = 0; ii < 4; ii++) {
      f4 u = U4[j * 4 + ((ii ^ (j >> 3)) & 3)];
      d += u[0]*X[4*ii] + u[1]*X[4*ii+1] + u[2]*X[4*ii+2] + u[3]*X[4*ii+3];
    }
    float cn = Cb[j * NN] + sc * d;
    Cb[j * NN] = cn;
    #pragma unroll
    for (int cc = 0; cc < 8; cc++) {
      f4 e = Es[j * 8 + ((cc ^ (j >> 3)) & 7)];
      lg[4*cc+0] += cn * e[0]; lg[4*cc+1] += cn * e[1];
      lg[4*cc+2] += cn * e[2]; lg[4*cc+3] += cn * e[3];
    }
  }
  // tree-reduce logits across the 8 j-octet lanes (same column)
  #pragma unroll
  for (int s = 1; s < 8; s <<= 1) {
    #pragma unroll
    for (int k = 0; k < 32; k++) lg[k] += __shfl_xor(lg[k], s, 64);
  }
  #define QUAD(gg) (f4){lg[4*(gg)], lg[4*(gg)+1], lg[4*(gg)+2], lg[4*(gg)+3]}
  f4 vlog;
  if (last) {
    switch (g) {
      case 0: vlog = QUAD(0); break;  case 1: vlog = QUAD(1); break;
      case 2: vlog = QUAD(2); break;  case 3: vlog = QUAD(3); break;
      case 4: vlog = QUAD(4); break;  case 5: vlog = QUAD(5); break;
      case 6: vlog = QUAD(6); break;  default: vlog = QUAD(7); break;
    }
  }
  float mx = lg[0];
  #pragma unroll
  for (int k = 1; k < 32; k++) mx = fmaxf(mx, lg[k]);
  float ssum = 0.f;
  #pragma unroll
  for (int k = 0; k < 32; k++) { lg[k] = __expf(lg[k] - mx); ssum += lg[k]; }
  float inv = 1.0f / ssum;
  #pragma unroll
  for (int k = 0; k < 32; k++) lg[k] *= inv;
  if (last) {
    f4 vpred;
    switch (g) {
      case 0: vpred = QUAD(0); break;  case 1: vpred = QUAD(1); break;
      case 2: vpred = QUAD(2); break;  case 3: vpred = QUAD(3); break;
      case 4: vpred = QUAD(4); break;  case 5: vpred = QUAD(5); break;
      case 6: vpred = QUAD(6); break;  default: vpred = QUAD(7); break;
    }
    float* lo = out + ((size_t)b * NN + m) * 32 + g * 4;
    float* po = lo + (size_t)NB * NN * 32;
    *reinterpret_cast<f4*>(lo) = vlog;
    *reinterpret_cast<f4*>(po) = vpred;
  }
  #undef QUAD
  // B update: rows g*8..g*8+7 of column m
  int nst = nstar[b * NN + m];
  const f4* BC = reinterpret_cast<const f4*>(Bin + ((size_t)b * NN + m) * 64 + g * 8);
  const f4* BG = reinterpret_cast<const f4*>(Bin + ((size_t)b * NN + nst) * 64 + g * 8);
  f4* BO = reinterpret_cast<f4*>(Bout + ((size_t)b * NN + m) * 64 + g * 8);
  const float invM = 1.0f / 1008.0f;
  #pragma unroll
  for (int jg = 0; jg < 2; jg++) {
    f4 bc4 = BC[jg];
    f4 bg4 = BG[jg];
    f4 vo;
    #pragma unroll
    for (int k = 0; k < 4; k++) {
      int j = g * 8 + jg * 4 + k;
      float v = bc4[k] - bg4[k] * invM;
      #pragma unroll
      for (int cc = 0; cc < 8; cc++) {
        f4 e = Es[j * 8 + ((cc ^ (j >> 3)) & 7)];
        v += e[0]*lg[4*cc] + e[1]*lg[4*cc+1] + e[2]*lg[4*cc+2] + e[3]*lg[4*cc+3];
      }
      vo[k] = v;
    }
    BO[jg] = vo;
  }
}

extern "C" void kernel_launch(void* const* d_in, const int* in_sizes, int n_in,
                              void* d_out, int out_size, void* d_ws, size_t ws_size,
                              hipStream_t stream)
{
  const float* x     = (const float*)d_in[0];
  const float* alpha = (const float*)d_in[1];
  const float* kp    = (const float*)d_in[2];
  const float* emb   = (const float*)d_in[3];
  float* ws = (float*)d_ws;
  float* A  = ws + OFF_A;
  float* B0 = ws + OFF_B0;
  float* B1 = ws + OFF_B1;
  float* C  = ws + OFF_C;
  float* Up = ws + OFF_UP;
  int*   ns = (int*)(ws + OFF_NS);
  float* out = (float*)d_out;

  k_init<<<1536, 256, 0, stream>>>(x, emb, A, B0, C, ns);
  float* Bbuf[2] = {B0, B1};
  for (int l = 0; l < 3; l++) {
    k_upart<<<512, 256, 0, stream>>>(x, alpha, l, A, Bbuf[l & 1], Up);
    k_update<<<1024, 256, 0, stream>>>(x, emb, kp, Up, ns, C, Bbuf[l & 1],
                                       Bbuf[(l + 1) & 1], (l == 2) ? 1 : 0, out);
  }
}